// Round 12
// baseline (460.663 us; speedup 1.0000x reference)
//
#include <hip/hip_runtime.h>
#include <math.h>

// GCN forward: 2x GCNConv (20->16->2) + ReLU + log_softmax
// N=100000 nodes, E=6400000 edges.
//
// Per layer (exact algebra of PyG GCNConv w/ self-loops):
//   y[i]   = (x[i] @ W) * dinv[i]
//   s[i]   = sum_{c in in-neighbors(i)} y[c]     (row-sorted CSR, register accum, NO atomics)
//   out[i] = dinv[i]*(s[i] + y[i]) + b           (self-loop = dinv^2 * xw)
//
// Contention/amplification lessons baked in:
//   - R3/R8: device-scope global atomics migrate lines across XCDs through
//     HBM. A 6.4M-atomic global histogram costs 255us/200MB standalone ->
//     recover degree inside the bucket sort (padded bhist + in-bucket dcnt).
//   - R4: per-edge-per-feature LDS float atomics are a wall -> row-sort once.
//   - R5/R6/R7: scattered 4B global writes suffer 4-7x HBM write
//     amplification under streaming reads. Only coalesced bursts are amp=1.
//     passA scatters into an LDS stage and bursts out. (Exception: passB's
//     placement into its private 32KB csr region: measured amp=1.0.)
//   - R6: y1 gather table in bf16 (3.2MB) -> fits per-XCD 4MiB L2.
//   - R9/R10: sort passes are LATENCY-bound: maximize segments in flight
//     and blocks/CU.
//   - R11: fusing bscan as "each block sums its prefix over line-padded
//     bhist" costs 19.5MB scattered reads (782 blocks x b lines) -> regressed.
//     R12: bucket scan done ONCE by the LAST passA block (atomic done-counter,
//     atomic-read of bhist) -> zero extra traffic, zero extra dispatch.
//
// Pipeline: passA (reg-held multisplit -> block-major csrtmp + lbt + padded
//   bhist; last block scans bhist -> bbase) -> passB (stitch + in-bucket
//   count/sort -> row-sorted csr + rowptr + dinv) -> xw1(bf16) ->
//   gather16(+hw2 -> y2) -> gather2.

#define XF 20
#define F1 16
#define F2 2
#define RPB 128           // rows per bucket (1<<7)
#define KMAX 800          // max buckets (N <= 102400)
#define KP   784          // lbt row stride (>= K+1)
#define TILE 8192         // edges per passA block
#define EPT 16            // edges per passA thread (TILE/512)
#define NJMAX 800         // max passA blocks/segments (E <= 6553600)
#define CAP 9216          // passB LDS stage (mean 8192, sigma ~90 -> +11 sigma)
#define BPAD 16           // bhist padding: 1 counter per 64B line

__device__ __forceinline__ unsigned bf16rne(float f) {
    unsigned u = __float_as_uint(f);
    return (u + 0x7FFFu + ((u >> 16) & 1u)) >> 16;
}
__device__ __forceinline__ float bflo(unsigned w) { return __uint_as_float(w << 16); }
__device__ __forceinline__ float bfhi(unsigned w) { return __uint_as_float(w & 0xFFFF0000u); }

// Multisplit with LDS staging: rows held in registers across hist+scatter
// phases (single read of rows). Scatter packed (c<<7)|(r&127) into 32KB LDS
// stage (bucket-major) -> coalesced BURST to csrtmp[e0..e1] (amp=1).
// Side outputs: lbt[blk][k] = local bucket start (entry K = tile count),
// bhist[k*BPAD] += count (padded global atomics). The LAST block to finish
// additionally scans bhist -> bbase (fused bscan, no extra dispatch).
__global__ __launch_bounds__(512) void passA_kernel(const int* __restrict__ rows,
                                                    const int* __restrict__ cols,
                                                    int* __restrict__ bhist,
                                                    int* __restrict__ lbt,
                                                    unsigned int* __restrict__ csrtmp,
                                                    int* __restrict__ bbase,
                                                    int* __restrict__ gdone,
                                                    int E, int K) {
    __shared__ unsigned int stage[TILE];  // 32KB
    __shared__ int hist[KMAX];            // counts -> cursors
    __shared__ int tsum[512];
    __shared__ int lastFlag;
    int t = threadIdx.x;
    int bj = blockIdx.x;
    for (int k = t; k < K; k += 512) hist[k] = 0;
    __syncthreads();
    int e0 = bj * TILE;
    int e1 = min(e0 + TILE, E);
    int n = e1 - e0;
    // phase 1: read rows once, hold in registers, build LDS histogram
    int rloc[EPT];
    #pragma unroll
    for (int it = 0; it < EPT; it++) {
        int e = e0 + it * 512 + t;
        if (e < e1) {
            int r = rows[e];
            rloc[it] = r;
            atomicAdd(&hist[r >> 7], 1);
        }
    }
    __syncthreads();
    // block-wide exclusive scan over K buckets (2 per thread)
    int k0 = 2 * t, k1 = 2 * t + 1;
    int v0 = (k0 < K) ? hist[k0] : 0;
    int v1 = (k1 < K) ? hist[k1] : 0;
    int s = v0 + v1;
    tsum[t] = s;
    __syncthreads();
    for (int d = 1; d < 512; d <<= 1) {
        int u = (t >= d) ? tsum[t - d] : 0;
        __syncthreads();
        tsum[t] += u;
        __syncthreads();
    }
    int run = tsum[t] - s;
    long long lrow = (long long)bj * KP;
    if (k0 < K) {
        hist[k0] = run;  lbt[lrow + k0] = run;
        if (v0) atomicAdd(&bhist[k0 * BPAD], v0);
    }
    if (k1 < K) {
        hist[k1] = run + v0;  lbt[lrow + k1] = run + v0;
        if (v1) atomicAdd(&bhist[k1 * BPAD], v1);
    }
    if (t == 0) lbt[lrow + K] = n;
    __syncthreads();
    // phase 2: scatter into LDS stage using register-held rows + fresh cols
    #pragma unroll
    for (int it = 0; it < EPT; it++) {
        int e = e0 + it * 512 + t;
        if (e < e1) {
            int r = rloc[it];
            int c = cols[e];
            int pos = atomicAdd(&hist[r >> 7], 1);
            stage[pos] = ((unsigned int)c << 7) | (unsigned int)(r & 127);
        }
    }
    __syncthreads();
    // coalesced burst out
    for (int ss = t; ss < n; ss += 512)
        csrtmp[(size_t)e0 + ss] = stage[ss];
    // ---- fused bscan: last block to retire scans bhist -> bbase ----
    __threadfence();
    __syncthreads();
    if (t == 0) lastFlag = (atomicAdd(gdone, 1) == (int)gridDim.x - 1);
    __syncthreads();
    if (lastFlag) {
        int w0 = (k0 < K) ? atomicAdd(&bhist[k0 * BPAD], 0) : 0;  // coherent read
        int w1 = (k1 < K) ? atomicAdd(&bhist[k1 * BPAD], 0) : 0;
        int ssum = w0 + w1;
        tsum[t] = ssum;
        __syncthreads();
        for (int d = 1; d < 512; d <<= 1) {
            int u = (t >= d) ? tsum[t - d] : 0;
            __syncthreads();
            tsum[t] += u;
            __syncthreads();
        }
        int rn = tsum[t] - ssum;
        if (k0 < K) bbase[k0] = rn;
        if (k1 < K) bbase[k1] = rn + w0;
        if (t == 0) bbase[K] = E;
    }
}

// One block per bucket, 512 threads: segment offsets up-front (2/thread),
// prefix-scan lengths -> stage positions; stitch with 8-lane sub-waves (64
// segments in flight) while counting rows; wave-scan -> rowptr/dinv/rp;
// place row-sorted into final csr (private 32KB region, amp=1.0 measured).
__global__ __launch_bounds__(512) void passB_kernel(const int* __restrict__ lbt,
                                                    const unsigned int* __restrict__ csrtmp,
                                                    const int* __restrict__ bbase,
                                                    unsigned int* __restrict__ csr,
                                                    int* __restrict__ rowptr,
                                                    float* __restrict__ dinv,
                                                    int N, int K, int E, int nj) {
    __shared__ unsigned int stage[CAP];
    __shared__ int segoff[NJMAX];
    __shared__ int stagepos[NJMAX + 1];
    __shared__ int dcnt[RPB];
    __shared__ int rp[RPB];
    __shared__ int cur[RPB];
    __shared__ int tsum[512];
    int b = blockIdx.x, t = threadIdx.x;
    int lo = b << 7;
    if (t < RPB) { dcnt[t] = 0; cur[t] = 0; }
    // two segments per thread (nj <= 800 <= 1024)
    int a0 = 2 * t, a1 = 2 * t + 1;
    int la = 0, lb2 = 0;
    if (a0 < nj) {
        const int* lp = lbt + (long long)a0 * KP + b;
        int o0 = lp[0], o1 = lp[1];
        segoff[a0] = o0; la = o1 - o0;
    }
    if (a1 < nj) {
        const int* lp = lbt + (long long)a1 * KP + b;
        int o0 = lp[0], o1 = lp[1];
        segoff[a1] = o0; lb2 = o1 - o0;
    }
    int s = la + lb2;
    tsum[t] = s;
    __syncthreads();
    for (int d = 1; d < 512; d <<= 1) {
        int u = (t >= d) ? tsum[t - d] : 0;
        __syncthreads();
        tsum[t] += u;
        __syncthreads();
    }
    int run = tsum[t] - s;               // reads own tsum[t] only
    if (a0 < nj) stagepos[a0] = run;
    if (a1 < nj) stagepos[a1] = run + la;
    if (t == 511) stagepos[nj] = tsum[511];
    __syncthreads();
    int cnt = min(stagepos[nj], CAP);
    // stitch: 64 sub-waves of 8 lanes, segments round-robin
    int sw = t >> 3, ln = t & 7;
    for (int seg = sw; seg < nj; seg += 64) {
        int sp = stagepos[seg];
        int len = stagepos[seg + 1] - sp;
        if (sp + len > CAP) len = max(0, CAP - sp);  // safety clamp
        size_t src = (size_t)seg * TILE + segoff[seg];
        for (int e2 = ln; e2 < len; e2 += 8) {
            unsigned int p = csrtmp[src + e2];
            stage[sp + e2] = p;
            atomicAdd(&dcnt[p & 127u], 1);
        }
    }
    __syncthreads();
    int gb = bbase[b];
    if (t < 64) {  // one wave scans 128 counters, 2 per lane
        int v0 = dcnt[2 * t], v1 = dcnt[2 * t + 1];
        int ss = v0 + v1;
        int sc = ss;
        #pragma unroll
        for (int d = 1; d < 64; d <<= 1) {
            int u = __shfl_up(sc, d);
            if (t >= d) sc += u;
        }
        int excl = gb + sc - ss;
        rp[2 * t] = excl;
        rp[2 * t + 1] = excl + v0;
        int i0 = lo + 2 * t, i1 = i0 + 1;
        if (i0 < N) { rowptr[i0] = excl;      dinv[i0] = rsqrtf((float)v0 + 1.0f); }
        if (i1 < N) { rowptr[i1] = excl + v0; dinv[i1] = rsqrtf((float)v1 + 1.0f); }
        if (t == 0 && b == K - 1) rowptr[N] = E;
    }
    __syncthreads();
    for (int ss = t; ss < cnt; ss += 512) {
        unsigned int p = stage[ss];
        int rr = (int)(p & 127u);
        int dst = rp[rr] + atomicAdd(&cur[rr], 1);
        csr[dst] = p >> 7;
    }
}

// y1h[i][j] = bf16( (sum_k x[i][k] * W1[k][j]) * dinv[i] )  -- 32B/row table
__global__ void xw1_kernel(const float* __restrict__ x, const float* __restrict__ W1,
                           const float* __restrict__ dinv, unsigned int* __restrict__ y1h,
                           int N) {
    __shared__ float Ws[XF * F1];
    for (int k = threadIdx.x; k < XF * F1; k += blockDim.x) Ws[k] = W1[k];
    __syncthreads();
    int i = blockIdx.x * blockDim.x + threadIdx.x;
    if (i >= N) return;
    const float4* xv = (const float4*)(x + (size_t)i * XF);
    float xr[XF];
    #pragma unroll
    for (int q = 0; q < 5; q++) {
        float4 v = xv[q];
        xr[q*4+0] = v.x; xr[q*4+1] = v.y; xr[q*4+2] = v.z; xr[q*4+3] = v.w;
    }
    float d = dinv[i];
    float out[F1];
    #pragma unroll
    for (int j = 0; j < F1; j++) {
        float a = 0.f;
        #pragma unroll
        for (int k = 0; k < XF; k++) a += xr[k] * Ws[k * F1 + j];
        out[j] = a * d;
    }
    unsigned int w[8];
    #pragma unroll
    for (int q = 0; q < 8; q++)
        w[q] = bf16rne(out[2*q]) | (bf16rne(out[2*q+1]) << 16);
    uint4* o = (uint4*)(y1h + (size_t)i * 8);
    o[0] = make_uint4(w[0], w[1], w[2], w[3]);
    o[1] = make_uint4(w[4], w[5], w[6], w[7]);
}

// One wave per row: 2 lanes/edge (8 bf16 features each), 32 edges in flight,
// register accumulation, shfl-xor reduce, fused ReLU + layer-2 MLP (hw2):
// h never materializes; lanes 0/1 compute y2[i] = (h_row @ W2) * dinv[i].
__global__ __launch_bounds__(256) void gather16_kernel(const int* __restrict__ rowptr,
                                                       const unsigned int* __restrict__ csr,
                                                       const unsigned int* __restrict__ y1h,
                                                       const float* __restrict__ dinv,
                                                       const float* __restrict__ b1,
                                                       const float* __restrict__ W2,
                                                       float* __restrict__ y2, int N) {
    __shared__ float W2s[F1 * F2];
    if (threadIdx.x < F1 * F2) W2s[threadIdx.x] = W2[threadIdx.x];
    __syncthreads();
    int wave = threadIdx.x >> 6;
    int lane = threadIdx.x & 63;
    int i = blockIdx.x * 4 + wave;
    if (i >= N) return;
    int half = lane & 1, es = lane >> 1;
    int start = rowptr[i], end = rowptr[i + 1];
    const uint4* Y = (const uint4*)y1h;
    float acc[8] = {0.f, 0.f, 0.f, 0.f, 0.f, 0.f, 0.f, 0.f};
    for (int slot = start + es; slot < end; slot += 32) {
        int c = (int)csr[slot];
        uint4 w = Y[(size_t)c * 2 + half];
        acc[0] += bflo(w.x); acc[1] += bfhi(w.x);
        acc[2] += bflo(w.y); acc[3] += bfhi(w.y);
        acc[4] += bflo(w.z); acc[5] += bfhi(w.z);
        acc[6] += bflo(w.w); acc[7] += bfhi(w.w);
    }
    #pragma unroll
    for (int m = 2; m <= 32; m <<= 1) {
        #pragma unroll
        for (int k = 0; k < 8; k++) acc[k] += __shfl_xor(acc[k], m);
    }
    if (lane < 2) {
        float d = dinv[i];
        uint4 w = Y[(size_t)i * 2 + lane];
        float self[8] = { bflo(w.x), bfhi(w.x), bflo(w.y), bfhi(w.y),
                          bflo(w.z), bfhi(w.z), bflo(w.w), bfhi(w.w) };
        float4 bl = ((const float4*)b1)[lane * 2];
        float4 bh = ((const float4*)b1)[lane * 2 + 1];
        float bb[8] = { bl.x, bl.y, bl.z, bl.w, bh.x, bh.y, bh.z, bh.w };
        float p0 = 0.f, p1 = 0.f;
        #pragma unroll
        for (int k = 0; k < 8; k++) {
            float hv = fmaxf(d * (acc[k] + self[k]) + bb[k], 0.f);  // h value
            p0 += hv * W2s[(lane * 8 + k) * 2];
            p1 += hv * W2s[(lane * 8 + k) * 2 + 1];
        }
        float q0 = __shfl_xor(p0, 1);
        float q1 = __shfl_xor(p1, 1);
        if (lane == 0)
            ((float2*)y2)[i] = make_float2((p0 + q0) * d, (p1 + q1) * d);
    }
}

// One wave per row: 1 lane/edge float2 gather, register accum, shfl reduce,
// fused log_softmax. Zero atomics. y2 = 800KB -> L2-resident.
__global__ __launch_bounds__(256) void gather2_kernel(const int* __restrict__ rowptr,
                                                      const unsigned int* __restrict__ csr,
                                                      const float* __restrict__ y2,
                                                      const float* __restrict__ dinv,
                                                      const float* __restrict__ b2,
                                                      float* __restrict__ out, int N) {
    int wave = threadIdx.x >> 6;
    int lane = threadIdx.x & 63;
    int i = blockIdx.x * 4 + wave;
    if (i >= N) return;
    int start = rowptr[i], end = rowptr[i + 1];
    float a0 = 0.f, a1 = 0.f;
    for (int slot = start + lane; slot < end; slot += 64) {
        int c = (int)csr[slot];
        float2 v = ((const float2*)y2)[c];
        a0 += v.x;
        a1 += v.y;
    }
    #pragma unroll
    for (int m = 32; m > 0; m >>= 1) {
        a0 += __shfl_xor(a0, m);
        a1 += __shfl_xor(a1, m);
    }
    if (lane == 0) {
        float d = dinv[i];
        float2 yi = ((const float2*)y2)[i];
        float v0 = d * (a0 + yi.x) + b2[0];
        float v1 = d * (a1 + yi.y) + b2[1];
        float mm = fmaxf(v0, v1);
        float lse = mm + logf(expf(v0 - mm) + expf(v1 - mm));
        ((float2*)out)[i] = make_float2(v0 - lse, v1 - lse);
    }
}

static inline size_t align256(size_t x) { return (x + 255) & ~(size_t)255; }

extern "C" void kernel_launch(void* const* d_in, const int* in_sizes, int n_in,
                              void* d_out, int out_size, void* d_ws, size_t ws_size,
                              hipStream_t stream) {
    const float* x  = (const float*)d_in[0];
    const int*   ei = (const int*)d_in[1];
    const float* W1 = (const float*)d_in[2];
    const float* b1 = (const float*)d_in[3];
    const float* W2 = (const float*)d_in[4];
    const float* b2 = (const float*)d_in[5];
    float* out = (float*)d_out;

    const int N = in_sizes[0] / XF;
    const int E = in_sizes[1] / 2;
    const int* rows = ei;
    const int* cols = ei + E;
    const int K = (N + RPB - 1) >> 7;        // 782 buckets for N=100000
    const int nj = (E + TILE - 1) / TILE;    // 782 passA blocks/segments

    // Workspace; zero-region first (padded bhist + gdone, 52KB memset).
    char* ws = (char*)d_ws;
    size_t off = 0;
    int*   bhist   = (int*)(ws + off);   off = align256(off + (size_t)KMAX * BPAD * 4);
    int*   gdone   = (int*)(ws + off);   off = align256(off + 256);
    size_t zero_bytes = off;
    int*   bbase   = (int*)(ws + off);   off = align256(off + (size_t)(KMAX + 1) * 4);
    int*   rowptr  = (int*)(ws + off);   off = align256(off + (size_t)(N + 1) * 4);
    float* dinv    = (float*)(ws + off); off = align256(off + (size_t)N * 4);
    int*   lbt     = (int*)(ws + off);   off = align256(off + (size_t)nj * KP * 4);
    unsigned int* csr = (unsigned int*)(ws + off); off = align256(off + (size_t)E * 4);
    // csrtmp is dead after passB -> y1h/y2 alias its region (xw1 runs after).
    size_t tmp0 = off;
    unsigned int* csrtmp = (unsigned int*)(ws + tmp0);
    unsigned int* y1h = (unsigned int*)(ws + tmp0);
    float* y2 = (float*)(ws + align256(tmp0 + (size_t)N * 8 * 4));

    hipMemsetAsync(d_ws, 0, zero_bytes, stream);

    const int B = 256;
    const int nbN = (N + B - 1) / B;   // 391
    const int nbW = (N + 3) / 4;       // 25000 (one wave per row)

    passA_kernel<<<nj, 512, 0, stream>>>(rows, cols, bhist, lbt, csrtmp, bbase, gdone, E, K);
    passB_kernel<<<K, 512, 0, stream>>>(lbt, csrtmp, bbase, csr, rowptr, dinv, N, K, E, nj);
    xw1_kernel<<<nbN, B, 0, stream>>>(x, W1, dinv, y1h, N);
    gather16_kernel<<<nbW, B, 0, stream>>>(rowptr, csr, y1h, dinv, b1, W2, y2, N);
    gather2_kernel<<<nbW, B, 0, stream>>>(rowptr, csr, y2, dinv, b2, out, N);
}

// Round 13
// 299.255 us; speedup vs baseline: 1.5394x; 1.5394x over previous
//
#include <hip/hip_runtime.h>
#include <math.h>

// GCN forward: 2x GCNConv (20->16->2) + ReLU + log_softmax
// N=100000 nodes, E=6400000 edges.
//
// Per layer (exact algebra of PyG GCNConv w/ self-loops):
//   y[i]   = (x[i] @ W) * dinv[i]
//   s[i]   = sum_{c in in-neighbors(i)} y[c]     (row-sorted CSR, register accum, NO atomics)
//   out[i] = dinv[i]*(s[i] + y[i]) + b           (self-loop = dinv^2 * xw)
//
// Contention/amplification lessons baked in:
//   - R3/R8: device-scope global atomics migrate lines across XCDs through
//     HBM. Never build a histogram with 6.4M global atomics standalone.
//   - R4: per-edge-per-feature LDS float atomics are a wall -> row-sort once.
//   - R5/R6/R7: scattered 4B global writes suffer 4-7x HBM write
//     amplification under streaming reads. Only coalesced bursts are amp=1.
//     passA scatters into an LDS stage and bursts out. (Exception: passB's
//     placement into its private 32KB csr region: measured amp=1.0.)
//   - R6: y1 gather table in bf16 (3.2MB) -> fits per-XCD 4MiB L2.
//   - R9/R10: sort passes are LATENCY-bound: maximize segments in flight
//     and blocks/CU.
//   - R11: per-block own-prefix bscan costs 19.5MB scattered reads -> no.
//   - R12: __threadfence() per block = per-XCD L2 WRITEBACK on CDNA4
//     (non-coherent L2s): passA 40->225us, write amp up. NEVER fence inside
//     a hot kernel; a separate 5us bscan dispatch is the right call.
//
// Pipeline: passA (reg-held multisplit -> block-major csrtmp + lbt + padded
//   bhist) -> bscan (bbase, tiny dispatch) -> passB (stitch + in-bucket
//   count/sort -> row-sorted csr + rowptr + dinv) -> xw1(bf16) ->
//   gather16(+hw2 -> y2) -> gather2.

#define XF 20
#define F1 16
#define F2 2
#define RPB 128           // rows per bucket (1<<7)
#define KMAX 800          // max buckets (N <= 102400)
#define KP   784          // lbt row stride (>= K+1)
#define TILE 8192         // edges per passA block
#define EPT 16            // edges per passA thread (TILE/512)
#define NJMAX 800         // max passA blocks/segments (E <= 6553600)
#define CAP 9216          // passB LDS stage (mean 8192, sigma ~90 -> +11 sigma)
#define BPAD 16           // bhist padding: 1 counter per 64B line

__device__ __forceinline__ unsigned bf16rne(float f) {
    unsigned u = __float_as_uint(f);
    return (u + 0x7FFFu + ((u >> 16) & 1u)) >> 16;
}
__device__ __forceinline__ float bflo(unsigned w) { return __uint_as_float(w << 16); }
__device__ __forceinline__ float bfhi(unsigned w) { return __uint_as_float(w & 0xFFFF0000u); }

// Multisplit with LDS staging: rows held in registers across hist+scatter
// phases (single read of rows). Scatter packed (c<<7)|(r&127) into 32KB LDS
// stage (bucket-major) -> coalesced BURST to csrtmp[e0..e1] (amp=1).
// Side outputs: lbt[blk][k] = local bucket start (entry K = tile count),
// bhist[k*BPAD] += count (padded global atomics). No fences (R12 lesson).
__global__ __launch_bounds__(512) void passA_kernel(const int* __restrict__ rows,
                                                    const int* __restrict__ cols,
                                                    int* __restrict__ bhist,
                                                    int* __restrict__ lbt,
                                                    unsigned int* __restrict__ csrtmp,
                                                    int E, int K) {
    __shared__ unsigned int stage[TILE];  // 32KB
    __shared__ int hist[KMAX];            // counts -> cursors
    __shared__ int tsum[512];
    int t = threadIdx.x;
    int bj = blockIdx.x;
    for (int k = t; k < K; k += 512) hist[k] = 0;
    __syncthreads();
    int e0 = bj * TILE;
    int e1 = min(e0 + TILE, E);
    int n = e1 - e0;
    // phase 1: read rows once, hold in registers, build LDS histogram
    int rloc[EPT];
    #pragma unroll
    for (int it = 0; it < EPT; it++) {
        int e = e0 + it * 512 + t;
        if (e < e1) {
            int r = rows[e];
            rloc[it] = r;
            atomicAdd(&hist[r >> 7], 1);
        }
    }
    __syncthreads();
    // block-wide exclusive scan over K buckets (2 per thread)
    int k0 = 2 * t, k1 = 2 * t + 1;
    int v0 = (k0 < K) ? hist[k0] : 0;
    int v1 = (k1 < K) ? hist[k1] : 0;
    int s = v0 + v1;
    tsum[t] = s;
    __syncthreads();
    for (int d = 1; d < 512; d <<= 1) {
        int u = (t >= d) ? tsum[t - d] : 0;
        __syncthreads();
        tsum[t] += u;
        __syncthreads();
    }
    int run = tsum[t] - s;
    long long lrow = (long long)bj * KP;
    if (k0 < K) {
        hist[k0] = run;  lbt[lrow + k0] = run;
        if (v0) atomicAdd(&bhist[k0 * BPAD], v0);
    }
    if (k1 < K) {
        hist[k1] = run + v0;  lbt[lrow + k1] = run + v0;
        if (v1) atomicAdd(&bhist[k1 * BPAD], v1);
    }
    if (t == 0) lbt[lrow + K] = n;
    __syncthreads();
    // phase 2: scatter into LDS stage using register-held rows + fresh cols
    #pragma unroll
    for (int it = 0; it < EPT; it++) {
        int e = e0 + it * 512 + t;
        if (e < e1) {
            int r = rloc[it];
            int c = cols[e];
            int pos = atomicAdd(&hist[r >> 7], 1);
            stage[pos] = ((unsigned int)c << 7) | (unsigned int)(r & 127);
        }
    }
    __syncthreads();
    // coalesced burst out
    for (int ss = t; ss < n; ss += 512)
        csrtmp[(size_t)e0 + ss] = stage[ss];
}

// One tiny block; 256 threads x 4 consecutive buckets each -> exclusive scan
// of the padded global histogram into bbase. ~5us, cheaper than any fusion.
__global__ void bscan_kernel(const int* __restrict__ bhist, int K, int E,
                             int* __restrict__ bbase) {
    __shared__ int tsum[256];
    int t = threadIdx.x;
    int vals[4];
    int s = 0;
    #pragma unroll
    for (int j = 0; j < 4; j++) {
        int idx = t * 4 + j;
        vals[j] = (idx < K) ? bhist[idx * BPAD] : 0;
        s += vals[j];
    }
    tsum[t] = s;
    __syncthreads();
    for (int d = 1; d < 256; d <<= 1) {
        int u = (t >= d) ? tsum[t - d] : 0;
        __syncthreads();
        tsum[t] += u;
        __syncthreads();
    }
    int run = tsum[t] - s;
    #pragma unroll
    for (int j = 0; j < 4; j++) {
        int idx = t * 4 + j;
        if (idx < K) bbase[idx] = run;
        run += vals[j];
    }
    if (t == 0) bbase[K] = E;
}

// One block per bucket, 512 threads: segment offsets up-front (2/thread),
// prefix-scan lengths -> stage positions; stitch with 8-lane sub-waves (64
// segments in flight) while counting rows; wave-scan -> rowptr/dinv/rp;
// place row-sorted into final csr (private 32KB region, amp=1.0 measured).
__global__ __launch_bounds__(512) void passB_kernel(const int* __restrict__ lbt,
                                                    const unsigned int* __restrict__ csrtmp,
                                                    const int* __restrict__ bbase,
                                                    unsigned int* __restrict__ csr,
                                                    int* __restrict__ rowptr,
                                                    float* __restrict__ dinv,
                                                    int N, int K, int E, int nj) {
    __shared__ unsigned int stage[CAP];
    __shared__ int segoff[NJMAX];
    __shared__ int stagepos[NJMAX + 1];
    __shared__ int dcnt[RPB];
    __shared__ int rp[RPB];
    __shared__ int cur[RPB];
    __shared__ int tsum[512];
    int b = blockIdx.x, t = threadIdx.x;
    int lo = b << 7;
    if (t < RPB) { dcnt[t] = 0; cur[t] = 0; }
    // two segments per thread (nj <= 800 <= 1024)
    int a0 = 2 * t, a1 = 2 * t + 1;
    int la = 0, lb2 = 0;
    if (a0 < nj) {
        const int* lp = lbt + (long long)a0 * KP + b;
        int o0 = lp[0], o1 = lp[1];
        segoff[a0] = o0; la = o1 - o0;
    }
    if (a1 < nj) {
        const int* lp = lbt + (long long)a1 * KP + b;
        int o0 = lp[0], o1 = lp[1];
        segoff[a1] = o0; lb2 = o1 - o0;
    }
    int s = la + lb2;
    tsum[t] = s;
    __syncthreads();
    for (int d = 1; d < 512; d <<= 1) {
        int u = (t >= d) ? tsum[t - d] : 0;
        __syncthreads();
        tsum[t] += u;
        __syncthreads();
    }
    int run = tsum[t] - s;               // reads own tsum[t] only
    if (a0 < nj) stagepos[a0] = run;
    if (a1 < nj) stagepos[a1] = run + la;
    if (t == 511) stagepos[nj] = tsum[511];
    __syncthreads();
    int cnt = min(stagepos[nj], CAP);
    // stitch: 64 sub-waves of 8 lanes, segments round-robin
    int sw = t >> 3, ln = t & 7;
    for (int seg = sw; seg < nj; seg += 64) {
        int sp = stagepos[seg];
        int len = stagepos[seg + 1] - sp;
        if (sp + len > CAP) len = max(0, CAP - sp);  // safety clamp
        size_t src = (size_t)seg * TILE + segoff[seg];
        for (int e2 = ln; e2 < len; e2 += 8) {
            unsigned int p = csrtmp[src + e2];
            stage[sp + e2] = p;
            atomicAdd(&dcnt[p & 127u], 1);
        }
    }
    __syncthreads();
    int gb = bbase[b];
    if (t < 64) {  // one wave scans 128 counters, 2 per lane
        int v0 = dcnt[2 * t], v1 = dcnt[2 * t + 1];
        int ss = v0 + v1;
        int sc = ss;
        #pragma unroll
        for (int d = 1; d < 64; d <<= 1) {
            int u = __shfl_up(sc, d);
            if (t >= d) sc += u;
        }
        int excl = gb + sc - ss;
        rp[2 * t] = excl;
        rp[2 * t + 1] = excl + v0;
        int i0 = lo + 2 * t, i1 = i0 + 1;
        if (i0 < N) { rowptr[i0] = excl;      dinv[i0] = rsqrtf((float)v0 + 1.0f); }
        if (i1 < N) { rowptr[i1] = excl + v0; dinv[i1] = rsqrtf((float)v1 + 1.0f); }
        if (t == 0 && b == K - 1) rowptr[N] = E;
    }
    __syncthreads();
    for (int ss = t; ss < cnt; ss += 512) {
        unsigned int p = stage[ss];
        int rr = (int)(p & 127u);
        int dst = rp[rr] + atomicAdd(&cur[rr], 1);
        csr[dst] = p >> 7;
    }
}

// y1h[i][j] = bf16( (sum_k x[i][k] * W1[k][j]) * dinv[i] )  -- 32B/row table
__global__ void xw1_kernel(const float* __restrict__ x, const float* __restrict__ W1,
                           const float* __restrict__ dinv, unsigned int* __restrict__ y1h,
                           int N) {
    __shared__ float Ws[XF * F1];
    for (int k = threadIdx.x; k < XF * F1; k += blockDim.x) Ws[k] = W1[k];
    __syncthreads();
    int i = blockIdx.x * blockDim.x + threadIdx.x;
    if (i >= N) return;
    const float4* xv = (const float4*)(x + (size_t)i * XF);
    float xr[XF];
    #pragma unroll
    for (int q = 0; q < 5; q++) {
        float4 v = xv[q];
        xr[q*4+0] = v.x; xr[q*4+1] = v.y; xr[q*4+2] = v.z; xr[q*4+3] = v.w;
    }
    float d = dinv[i];
    float out[F1];
    #pragma unroll
    for (int j = 0; j < F1; j++) {
        float a = 0.f;
        #pragma unroll
        for (int k = 0; k < XF; k++) a += xr[k] * Ws[k * F1 + j];
        out[j] = a * d;
    }
    unsigned int w[8];
    #pragma unroll
    for (int q = 0; q < 8; q++)
        w[q] = bf16rne(out[2*q]) | (bf16rne(out[2*q+1]) << 16);
    uint4* o = (uint4*)(y1h + (size_t)i * 8);
    o[0] = make_uint4(w[0], w[1], w[2], w[3]);
    o[1] = make_uint4(w[4], w[5], w[6], w[7]);
}

// One wave per row: 2 lanes/edge (8 bf16 features each), 32 edges in flight,
// register accumulation, shfl-xor reduce, fused ReLU + layer-2 MLP (hw2):
// h never materializes; lanes 0/1 compute y2[i] = (h_row @ W2) * dinv[i].
__global__ __launch_bounds__(256) void gather16_kernel(const int* __restrict__ rowptr,
                                                       const unsigned int* __restrict__ csr,
                                                       const unsigned int* __restrict__ y1h,
                                                       const float* __restrict__ dinv,
                                                       const float* __restrict__ b1,
                                                       const float* __restrict__ W2,
                                                       float* __restrict__ y2, int N) {
    __shared__ float W2s[F1 * F2];
    if (threadIdx.x < F1 * F2) W2s[threadIdx.x] = W2[threadIdx.x];
    __syncthreads();
    int wave = threadIdx.x >> 6;
    int lane = threadIdx.x & 63;
    int i = blockIdx.x * 4 + wave;
    if (i >= N) return;
    int half = lane & 1, es = lane >> 1;
    int start = rowptr[i], end = rowptr[i + 1];
    const uint4* Y = (const uint4*)y1h;
    float acc[8] = {0.f, 0.f, 0.f, 0.f, 0.f, 0.f, 0.f, 0.f};
    for (int slot = start + es; slot < end; slot += 32) {
        int c = (int)csr[slot];
        uint4 w = Y[(size_t)c * 2 + half];
        acc[0] += bflo(w.x); acc[1] += bfhi(w.x);
        acc[2] += bflo(w.y); acc[3] += bfhi(w.y);
        acc[4] += bflo(w.z); acc[5] += bfhi(w.z);
        acc[6] += bflo(w.w); acc[7] += bfhi(w.w);
    }
    #pragma unroll
    for (int m = 2; m <= 32; m <<= 1) {
        #pragma unroll
        for (int k = 0; k < 8; k++) acc[k] += __shfl_xor(acc[k], m);
    }
    if (lane < 2) {
        float d = dinv[i];
        uint4 w = Y[(size_t)i * 2 + lane];
        float self[8] = { bflo(w.x), bfhi(w.x), bflo(w.y), bfhi(w.y),
                          bflo(w.z), bfhi(w.z), bflo(w.w), bfhi(w.w) };
        float4 bl = ((const float4*)b1)[lane * 2];
        float4 bh = ((const float4*)b1)[lane * 2 + 1];
        float bb[8] = { bl.x, bl.y, bl.z, bl.w, bh.x, bh.y, bh.z, bh.w };
        float p0 = 0.f, p1 = 0.f;
        #pragma unroll
        for (int k = 0; k < 8; k++) {
            float hv = fmaxf(d * (acc[k] + self[k]) + bb[k], 0.f);  // h value
            p0 += hv * W2s[(lane * 8 + k) * 2];
            p1 += hv * W2s[(lane * 8 + k) * 2 + 1];
        }
        float q0 = __shfl_xor(p0, 1);
        float q1 = __shfl_xor(p1, 1);
        if (lane == 0)
            ((float2*)y2)[i] = make_float2((p0 + q0) * d, (p1 + q1) * d);
    }
}

// One wave per row: 1 lane/edge float2 gather, register accum, shfl reduce,
// fused log_softmax. Zero atomics. y2 = 800KB -> L2-resident.
__global__ __launch_bounds__(256) void gather2_kernel(const int* __restrict__ rowptr,
                                                      const unsigned int* __restrict__ csr,
                                                      const float* __restrict__ y2,
                                                      const float* __restrict__ dinv,
                                                      const float* __restrict__ b2,
                                                      float* __restrict__ out, int N) {
    int wave = threadIdx.x >> 6;
    int lane = threadIdx.x & 63;
    int i = blockIdx.x * 4 + wave;
    if (i >= N) return;
    int start = rowptr[i], end = rowptr[i + 1];
    float a0 = 0.f, a1 = 0.f;
    for (int slot = start + lane; slot < end; slot += 64) {
        int c = (int)csr[slot];
        float2 v = ((const float2*)y2)[c];
        a0 += v.x;
        a1 += v.y;
    }
    #pragma unroll
    for (int m = 32; m > 0; m >>= 1) {
        a0 += __shfl_xor(a0, m);
        a1 += __shfl_xor(a1, m);
    }
    if (lane == 0) {
        float d = dinv[i];
        float2 yi = ((const float2*)y2)[i];
        float v0 = d * (a0 + yi.x) + b2[0];
        float v1 = d * (a1 + yi.y) + b2[1];
        float mm = fmaxf(v0, v1);
        float lse = mm + logf(expf(v0 - mm) + expf(v1 - mm));
        ((float2*)out)[i] = make_float2(v0 - lse, v1 - lse);
    }
}

static inline size_t align256(size_t x) { return (x + 255) & ~(size_t)255; }

extern "C" void kernel_launch(void* const* d_in, const int* in_sizes, int n_in,
                              void* d_out, int out_size, void* d_ws, size_t ws_size,
                              hipStream_t stream) {
    const float* x  = (const float*)d_in[0];
    const int*   ei = (const int*)d_in[1];
    const float* W1 = (const float*)d_in[2];
    const float* b1 = (const float*)d_in[3];
    const float* W2 = (const float*)d_in[4];
    const float* b2 = (const float*)d_in[5];
    float* out = (float*)d_out;

    const int N = in_sizes[0] / XF;
    const int E = in_sizes[1] / 2;
    const int* rows = ei;
    const int* cols = ei + E;
    const int K = (N + RPB - 1) >> 7;        // 782 buckets for N=100000
    const int nj = (E + TILE - 1) / TILE;    // 782 passA blocks/segments

    // Workspace; zero-region first (padded bhist, 51KB memset).
    char* ws = (char*)d_ws;
    size_t off = 0;
    int*   bhist   = (int*)(ws + off);   off = align256(off + (size_t)KMAX * BPAD * 4);
    size_t zero_bytes = off;
    int*   bbase   = (int*)(ws + off);   off = align256(off + (size_t)(KMAX + 1) * 4);
    int*   rowptr  = (int*)(ws + off);   off = align256(off + (size_t)(N + 1) * 4);
    float* dinv    = (float*)(ws + off); off = align256(off + (size_t)N * 4);
    int*   lbt     = (int*)(ws + off);   off = align256(off + (size_t)nj * KP * 4);
    unsigned int* csr = (unsigned int*)(ws + off); off = align256(off + (size_t)E * 4);
    // csrtmp is dead after passB -> y1h/y2 alias its region (xw1 runs after).
    size_t tmp0 = off;
    unsigned int* csrtmp = (unsigned int*)(ws + tmp0);
    unsigned int* y1h = (unsigned int*)(ws + tmp0);
    float* y2 = (float*)(ws + align256(tmp0 + (size_t)N * 8 * 4));

    hipMemsetAsync(d_ws, 0, zero_bytes, stream);

    const int B = 256;
    const int nbN = (N + B - 1) / B;   // 391
    const int nbW = (N + 3) / 4;       // 25000 (one wave per row)

    passA_kernel<<<nj, 512, 0, stream>>>(rows, cols, bhist, lbt, csrtmp, E, K);
    bscan_kernel<<<1, B, 0, stream>>>(bhist, K, E, bbase);
    passB_kernel<<<K, 512, 0, stream>>>(lbt, csrtmp, bbase, csr, rowptr, dinv, N, K, E, nj);
    xw1_kernel<<<nbN, B, 0, stream>>>(x, W1, dinv, y1h, N);
    gather16_kernel<<<nbW, B, 0, stream>>>(rowptr, csr, y1h, dinv, b1, W2, y2, N);
    gather2_kernel<<<nbW, B, 0, stream>>>(rowptr, csr, y2, dinv, b2, out, N);
}

// Round 14
// 277.979 us; speedup vs baseline: 1.6572x; 1.0765x over previous
//
#include <hip/hip_runtime.h>
#include <math.h>

// GCN forward: 2x GCNConv (20->16->2) + ReLU + log_softmax
// N=100000 nodes, E=6400000 edges.
//
// Per layer (exact algebra of PyG GCNConv w/ self-loops):
//   y[i]   = (x[i] @ W) * dinv[i]
//   s[i]   = sum_{c in in-neighbors(i)} y[c]     (row-sorted CSR, register accum, NO atomics)
//   out[i] = dinv[i]*(s[i] + y[i]) + b           (self-loop = dinv^2 * xw)
//
// Contention/amplification lessons baked in:
//   - R3/R8: device-scope global atomics migrate lines across XCDs through
//     HBM. Never build a histogram with 6.4M global atomics standalone.
//   - R4: per-edge-per-feature LDS float atomics are a wall -> row-sort once.
//   - R5/R6/R7: scattered 4B global writes suffer 4-7x HBM write
//     amplification under streaming reads. Only coalesced bursts are amp=1.
//     passA scatters into an LDS stage and bursts out. (Exception: passB's
//     placement into its private 32KB csr region: measured amp=1.0.)
//   - R6: y1 gather table in bf16 (3.2MB) -> fits per-XCD 4MiB L2.
//   - R9/R10: sort passes are LATENCY-bound: maximize streams in flight.
//   - R11: per-block own-prefix bscan costs 19.5MB scattered reads -> no.
//   - R12: __threadfence() per block = per-XCD L2 WRITEBACK on CDNA4:
//     passA 40->225us. NEVER fence in a hot kernel; 5us bscan dispatch wins.
//   - R13: gathers are latency-bound at VALU 48% -> R14: 2 rows per wave
//     (32 lanes/row): 2 independent load streams per wave + 1 fewer
//     butterfly level.
//
// Pipeline: passA (reg-held multisplit -> block-major csrtmp + lbt + padded
//   bhist) -> bscan (bbase, tiny dispatch) -> passB (stitch + in-bucket
//   count/sort -> row-sorted csr + rowptr + dinv) -> xw1(bf16) ->
//   gather16(+hw2 -> y2) -> gather2.

#define XF 20
#define F1 16
#define F2 2
#define RPB 128           // rows per bucket (1<<7)
#define KMAX 800          // max buckets (N <= 102400)
#define KP   784          // lbt row stride (>= K+1)
#define TILE 8192         // edges per passA block
#define EPT 16            // edges per passA thread (TILE/512)
#define NJMAX 800         // max passA blocks/segments (E <= 6553600)
#define CAP 9216          // passB LDS stage (mean 8192, sigma ~90 -> +11 sigma)
#define BPAD 16           // bhist padding: 1 counter per 64B line

__device__ __forceinline__ unsigned bf16rne(float f) {
    unsigned u = __float_as_uint(f);
    return (u + 0x7FFFu + ((u >> 16) & 1u)) >> 16;
}
__device__ __forceinline__ float bflo(unsigned w) { return __uint_as_float(w << 16); }
__device__ __forceinline__ float bfhi(unsigned w) { return __uint_as_float(w & 0xFFFF0000u); }

// Multisplit with LDS staging: rows held in registers across hist+scatter
// phases (single read of rows). Scatter packed (c<<7)|(r&127) into 32KB LDS
// stage (bucket-major) -> coalesced BURST to csrtmp[e0..e1] (amp=1).
// Side outputs: lbt[blk][k] = local bucket start (entry K = tile count),
// bhist[k*BPAD] += count (padded global atomics). No fences (R12 lesson).
__global__ __launch_bounds__(512) void passA_kernel(const int* __restrict__ rows,
                                                    const int* __restrict__ cols,
                                                    int* __restrict__ bhist,
                                                    int* __restrict__ lbt,
                                                    unsigned int* __restrict__ csrtmp,
                                                    int E, int K) {
    __shared__ unsigned int stage[TILE];  // 32KB
    __shared__ int hist[KMAX];            // counts -> cursors
    __shared__ int tsum[512];
    int t = threadIdx.x;
    int bj = blockIdx.x;
    for (int k = t; k < K; k += 512) hist[k] = 0;
    __syncthreads();
    int e0 = bj * TILE;
    int e1 = min(e0 + TILE, E);
    int n = e1 - e0;
    // phase 1: read rows once, hold in registers, build LDS histogram
    int rloc[EPT];
    #pragma unroll
    for (int it = 0; it < EPT; it++) {
        int e = e0 + it * 512 + t;
        if (e < e1) {
            int r = rows[e];
            rloc[it] = r;
            atomicAdd(&hist[r >> 7], 1);
        }
    }
    __syncthreads();
    // block-wide exclusive scan over K buckets (2 per thread)
    int k0 = 2 * t, k1 = 2 * t + 1;
    int v0 = (k0 < K) ? hist[k0] : 0;
    int v1 = (k1 < K) ? hist[k1] : 0;
    int s = v0 + v1;
    tsum[t] = s;
    __syncthreads();
    for (int d = 1; d < 512; d <<= 1) {
        int u = (t >= d) ? tsum[t - d] : 0;
        __syncthreads();
        tsum[t] += u;
        __syncthreads();
    }
    int run = tsum[t] - s;
    long long lrow = (long long)bj * KP;
    if (k0 < K) {
        hist[k0] = run;  lbt[lrow + k0] = run;
        if (v0) atomicAdd(&bhist[k0 * BPAD], v0);
    }
    if (k1 < K) {
        hist[k1] = run + v0;  lbt[lrow + k1] = run + v0;
        if (v1) atomicAdd(&bhist[k1 * BPAD], v1);
    }
    if (t == 0) lbt[lrow + K] = n;
    __syncthreads();
    // phase 2: scatter into LDS stage using register-held rows + fresh cols
    #pragma unroll
    for (int it = 0; it < EPT; it++) {
        int e = e0 + it * 512 + t;
        if (e < e1) {
            int r = rloc[it];
            int c = cols[e];
            int pos = atomicAdd(&hist[r >> 7], 1);
            stage[pos] = ((unsigned int)c << 7) | (unsigned int)(r & 127);
        }
    }
    __syncthreads();
    // coalesced burst out
    for (int ss = t; ss < n; ss += 512)
        csrtmp[(size_t)e0 + ss] = stage[ss];
}

// One tiny block; 256 threads x 4 consecutive buckets each -> exclusive scan
// of the padded global histogram into bbase. ~5us, cheaper than any fusion.
__global__ void bscan_kernel(const int* __restrict__ bhist, int K, int E,
                             int* __restrict__ bbase) {
    __shared__ int tsum[256];
    int t = threadIdx.x;
    int vals[4];
    int s = 0;
    #pragma unroll
    for (int j = 0; j < 4; j++) {
        int idx = t * 4 + j;
        vals[j] = (idx < K) ? bhist[idx * BPAD] : 0;
        s += vals[j];
    }
    tsum[t] = s;
    __syncthreads();
    for (int d = 1; d < 256; d <<= 1) {
        int u = (t >= d) ? tsum[t - d] : 0;
        __syncthreads();
        tsum[t] += u;
        __syncthreads();
    }
    int run = tsum[t] - s;
    #pragma unroll
    for (int j = 0; j < 4; j++) {
        int idx = t * 4 + j;
        if (idx < K) bbase[idx] = run;
        run += vals[j];
    }
    if (t == 0) bbase[K] = E;
}

// One block per bucket, 512 threads: segment offsets up-front (2/thread),
// prefix-scan lengths -> stage positions; stitch with 8-lane sub-waves (64
// segments in flight) while counting rows; wave-scan -> rowptr/dinv/rp;
// place row-sorted into final csr (private 32KB region, amp=1.0 measured).
__global__ __launch_bounds__(512) void passB_kernel(const int* __restrict__ lbt,
                                                    const unsigned int* __restrict__ csrtmp,
                                                    const int* __restrict__ bbase,
                                                    unsigned int* __restrict__ csr,
                                                    int* __restrict__ rowptr,
                                                    float* __restrict__ dinv,
                                                    int N, int K, int E, int nj) {
    __shared__ unsigned int stage[CAP];
    __shared__ int segoff[NJMAX];
    __shared__ int stagepos[NJMAX + 1];
    __shared__ int dcnt[RPB];
    __shared__ int rp[RPB];
    __shared__ int cur[RPB];
    __shared__ int tsum[512];
    int b = blockIdx.x, t = threadIdx.x;
    int lo = b << 7;
    if (t < RPB) { dcnt[t] = 0; cur[t] = 0; }
    // two segments per thread (nj <= 800 <= 1024)
    int a0 = 2 * t, a1 = 2 * t + 1;
    int la = 0, lb2 = 0;
    if (a0 < nj) {
        const int* lp = lbt + (long long)a0 * KP + b;
        int o0 = lp[0], o1 = lp[1];
        segoff[a0] = o0; la = o1 - o0;
    }
    if (a1 < nj) {
        const int* lp = lbt + (long long)a1 * KP + b;
        int o0 = lp[0], o1 = lp[1];
        segoff[a1] = o0; lb2 = o1 - o0;
    }
    int s = la + lb2;
    tsum[t] = s;
    __syncthreads();
    for (int d = 1; d < 512; d <<= 1) {
        int u = (t >= d) ? tsum[t - d] : 0;
        __syncthreads();
        tsum[t] += u;
        __syncthreads();
    }
    int run = tsum[t] - s;               // reads own tsum[t] only
    if (a0 < nj) stagepos[a0] = run;
    if (a1 < nj) stagepos[a1] = run + la;
    if (t == 511) stagepos[nj] = tsum[511];
    __syncthreads();
    int cnt = min(stagepos[nj], CAP);
    // stitch: 64 sub-waves of 8 lanes, segments round-robin
    int sw = t >> 3, ln = t & 7;
    for (int seg = sw; seg < nj; seg += 64) {
        int sp = stagepos[seg];
        int len = stagepos[seg + 1] - sp;
        if (sp + len > CAP) len = max(0, CAP - sp);  // safety clamp
        size_t src = (size_t)seg * TILE + segoff[seg];
        for (int e2 = ln; e2 < len; e2 += 8) {
            unsigned int p = csrtmp[src + e2];
            stage[sp + e2] = p;
            atomicAdd(&dcnt[p & 127u], 1);
        }
    }
    __syncthreads();
    int gb = bbase[b];
    if (t < 64) {  // one wave scans 128 counters, 2 per lane
        int v0 = dcnt[2 * t], v1 = dcnt[2 * t + 1];
        int ss = v0 + v1;
        int sc = ss;
        #pragma unroll
        for (int d = 1; d < 64; d <<= 1) {
            int u = __shfl_up(sc, d);
            if (t >= d) sc += u;
        }
        int excl = gb + sc - ss;
        rp[2 * t] = excl;
        rp[2 * t + 1] = excl + v0;
        int i0 = lo + 2 * t, i1 = i0 + 1;
        if (i0 < N) { rowptr[i0] = excl;      dinv[i0] = rsqrtf((float)v0 + 1.0f); }
        if (i1 < N) { rowptr[i1] = excl + v0; dinv[i1] = rsqrtf((float)v1 + 1.0f); }
        if (t == 0 && b == K - 1) rowptr[N] = E;
    }
    __syncthreads();
    for (int ss = t; ss < cnt; ss += 512) {
        unsigned int p = stage[ss];
        int rr = (int)(p & 127u);
        int dst = rp[rr] + atomicAdd(&cur[rr], 1);
        csr[dst] = p >> 7;
    }
}

// y1h[i][j] = bf16( (sum_k x[i][k] * W1[k][j]) * dinv[i] )  -- 32B/row table
__global__ void xw1_kernel(const float* __restrict__ x, const float* __restrict__ W1,
                           const float* __restrict__ dinv, unsigned int* __restrict__ y1h,
                           int N) {
    __shared__ float Ws[XF * F1];
    for (int k = threadIdx.x; k < XF * F1; k += blockDim.x) Ws[k] = W1[k];
    __syncthreads();
    int i = blockIdx.x * blockDim.x + threadIdx.x;
    if (i >= N) return;
    const float4* xv = (const float4*)(x + (size_t)i * XF);
    float xr[XF];
    #pragma unroll
    for (int q = 0; q < 5; q++) {
        float4 v = xv[q];
        xr[q*4+0] = v.x; xr[q*4+1] = v.y; xr[q*4+2] = v.z; xr[q*4+3] = v.w;
    }
    float d = dinv[i];
    float out[F1];
    #pragma unroll
    for (int j = 0; j < F1; j++) {
        float a = 0.f;
        #pragma unroll
        for (int k = 0; k < XF; k++) a += xr[k] * Ws[k * F1 + j];
        out[j] = a * d;
    }
    unsigned int w[8];
    #pragma unroll
    for (int q = 0; q < 8; q++)
        w[q] = bf16rne(out[2*q]) | (bf16rne(out[2*q+1]) << 16);
    uint4* o = (uint4*)(y1h + (size_t)i * 8);
    o[0] = make_uint4(w[0], w[1], w[2], w[3]);
    o[1] = make_uint4(w[4], w[5], w[6], w[7]);
}

// TWO rows per wave (32 lanes each): 2 lanes/edge (8 bf16 features each),
// 16 edges in flight per row, 2 independent load streams per wave.
// Butterfly masks 2..16 stay within the 32-lane half. Fused ReLU + hw2:
// h never materializes; lanes 0/1 of each half compute y2[i].
__global__ __launch_bounds__(256) void gather16_kernel(const int* __restrict__ rowptr,
                                                       const unsigned int* __restrict__ csr,
                                                       const unsigned int* __restrict__ y1h,
                                                       const float* __restrict__ dinv,
                                                       const float* __restrict__ b1,
                                                       const float* __restrict__ W2,
                                                       float* __restrict__ y2, int N) {
    __shared__ float W2s[F1 * F2];
    if (threadIdx.x < F1 * F2) W2s[threadIdx.x] = W2[threadIdx.x];
    __syncthreads();
    int sub = threadIdx.x >> 5;       // 8 half-waves per block
    int l = threadIdx.x & 31;
    int i = blockIdx.x * 8 + sub;
    if (i >= N) return;
    int half = l & 1, es = l >> 1;    // 16 edges in flight
    int start = rowptr[i], end = rowptr[i + 1];
    const uint4* Y = (const uint4*)y1h;
    float acc[8] = {0.f, 0.f, 0.f, 0.f, 0.f, 0.f, 0.f, 0.f};
    for (int slot = start + es; slot < end; slot += 16) {
        int c = (int)csr[slot];
        uint4 w = Y[(size_t)c * 2 + half];
        acc[0] += bflo(w.x); acc[1] += bfhi(w.x);
        acc[2] += bflo(w.y); acc[3] += bfhi(w.y);
        acc[4] += bflo(w.z); acc[5] += bfhi(w.z);
        acc[6] += bflo(w.w); acc[7] += bfhi(w.w);
    }
    #pragma unroll
    for (int m = 2; m <= 16; m <<= 1) {
        #pragma unroll
        for (int k = 0; k < 8; k++) acc[k] += __shfl_xor(acc[k], m);
    }
    if (l < 2) {
        float d = dinv[i];
        uint4 w = Y[(size_t)i * 2 + l];
        float self[8] = { bflo(w.x), bfhi(w.x), bflo(w.y), bfhi(w.y),
                          bflo(w.z), bfhi(w.z), bflo(w.w), bfhi(w.w) };
        float4 bl = ((const float4*)b1)[l * 2];
        float4 bh = ((const float4*)b1)[l * 2 + 1];
        float bb[8] = { bl.x, bl.y, bl.z, bl.w, bh.x, bh.y, bh.z, bh.w };
        float p0 = 0.f, p1 = 0.f;
        #pragma unroll
        for (int k = 0; k < 8; k++) {
            float hv = fmaxf(d * (acc[k] + self[k]) + bb[k], 0.f);  // h value
            p0 += hv * W2s[(l * 8 + k) * 2];
            p1 += hv * W2s[(l * 8 + k) * 2 + 1];
        }
        float q0 = __shfl_xor(p0, 1);
        float q1 = __shfl_xor(p1, 1);
        if (l == 0)
            ((float2*)y2)[i] = make_float2((p0 + q0) * d, (p1 + q1) * d);
    }
}

// TWO rows per wave (32 lanes each): 1 lane/edge float2 gather, masks 16..1
// butterfly, fused log_softmax. Zero atomics. y2 = 800KB -> L2-resident.
__global__ __launch_bounds__(256) void gather2_kernel(const int* __restrict__ rowptr,
                                                      const unsigned int* __restrict__ csr,
                                                      const float* __restrict__ y2,
                                                      const float* __restrict__ dinv,
                                                      const float* __restrict__ b2,
                                                      float* __restrict__ out, int N) {
    int sub = threadIdx.x >> 5;       // 8 half-waves per block
    int l = threadIdx.x & 31;
    int i = blockIdx.x * 8 + sub;
    if (i >= N) return;
    int start = rowptr[i], end = rowptr[i + 1];
    float a0 = 0.f, a1 = 0.f;
    for (int slot = start + l; slot < end; slot += 32) {
        int c = (int)csr[slot];
        float2 v = ((const float2*)y2)[c];
        a0 += v.x;
        a1 += v.y;
    }
    #pragma unroll
    for (int m = 16; m > 0; m >>= 1) {
        a0 += __shfl_xor(a0, m);
        a1 += __shfl_xor(a1, m);
    }
    if (l == 0) {
        float d = dinv[i];
        float2 yi = ((const float2*)y2)[i];
        float v0 = d * (a0 + yi.x) + b2[0];
        float v1 = d * (a1 + yi.y) + b2[1];
        float mm = fmaxf(v0, v1);
        float lse = mm + logf(expf(v0 - mm) + expf(v1 - mm));
        ((float2*)out)[i] = make_float2(v0 - lse, v1 - lse);
    }
}

static inline size_t align256(size_t x) { return (x + 255) & ~(size_t)255; }

extern "C" void kernel_launch(void* const* d_in, const int* in_sizes, int n_in,
                              void* d_out, int out_size, void* d_ws, size_t ws_size,
                              hipStream_t stream) {
    const float* x  = (const float*)d_in[0];
    const int*   ei = (const int*)d_in[1];
    const float* W1 = (const float*)d_in[2];
    const float* b1 = (const float*)d_in[3];
    const float* W2 = (const float*)d_in[4];
    const float* b2 = (const float*)d_in[5];
    float* out = (float*)d_out;

    const int N = in_sizes[0] / XF;
    const int E = in_sizes[1] / 2;
    const int* rows = ei;
    const int* cols = ei + E;
    const int K = (N + RPB - 1) >> 7;        // 782 buckets for N=100000
    const int nj = (E + TILE - 1) / TILE;    // 782 passA blocks/segments

    // Workspace; zero-region first (padded bhist, 51KB memset).
    char* ws = (char*)d_ws;
    size_t off = 0;
    int*   bhist   = (int*)(ws + off);   off = align256(off + (size_t)KMAX * BPAD * 4);
    size_t zero_bytes = off;
    int*   bbase   = (int*)(ws + off);   off = align256(off + (size_t)(KMAX + 1) * 4);
    int*   rowptr  = (int*)(ws + off);   off = align256(off + (size_t)(N + 1) * 4);
    float* dinv    = (float*)(ws + off); off = align256(off + (size_t)N * 4);
    int*   lbt     = (int*)(ws + off);   off = align256(off + (size_t)nj * KP * 4);
    unsigned int* csr = (unsigned int*)(ws + off); off = align256(off + (size_t)E * 4);
    // csrtmp is dead after passB -> y1h/y2 alias its region (xw1 runs after).
    size_t tmp0 = off;
    unsigned int* csrtmp = (unsigned int*)(ws + tmp0);
    unsigned int* y1h = (unsigned int*)(ws + tmp0);
    float* y2 = (float*)(ws + align256(tmp0 + (size_t)N * 8 * 4));

    hipMemsetAsync(d_ws, 0, zero_bytes, stream);

    const int B = 256;
    const int nbN = (N + B - 1) / B;   // 391
    const int nbW = (N + 7) / 8;       // 12500 (two rows per wave)

    passA_kernel<<<nj, 512, 0, stream>>>(rows, cols, bhist, lbt, csrtmp, E, K);
    bscan_kernel<<<1, B, 0, stream>>>(bhist, K, E, bbase);
    passB_kernel<<<K, 512, 0, stream>>>(lbt, csrtmp, bbase, csr, rowptr, dinv, N, K, E, nj);
    xw1_kernel<<<nbN, B, 0, stream>>>(x, W1, dinv, y1h, N);
    gather16_kernel<<<nbW, B, 0, stream>>>(rowptr, csr, y1h, dinv, b1, W2, y2, N);
    gather2_kernel<<<nbW, B, 0, stream>>>(rowptr, csr, y2, dinv, b2, out, N);
}